// Round 6
// baseline (188.780 us; speedup 1.0000x reference)
//
#include <hip/hip_runtime.h>

// loss = sum_i ( -2*logits[i, t_i] + top1_i + top2_i )
// (log_softmax's lse cancels exactly: -2(x_t - lse) + (m1 - lse) + (m2 - lse)
//  = m1 + m2 - 2 x_t, since CONTRASTIVE_NUM == 2 == broadcast count)
// Harness delivers integer inputs as int32.
//
// R6: R5 + persistent blocks. 512 blocks x 1024 threads (exactly co-resident,
// 2 blocks/CU), each handles 16 CONSECUTIVE rows -> one sequential 2 MB
// HBM stream per block, no block churn (was 8192 short-lived blocks).

#define NROWS 8192
#define VOCAB 32000
#define TPB 1024
#define NWAVES (TPB / 64)
#define NBLOCKS 512
#define ROWS_PER_BLOCK (NROWS / NBLOCKS)   // 16

__global__ __launch_bounds__(TPB) void cce_row_kernel(const float* __restrict__ logits,
                                                      const int* __restrict__ target,
                                                      float* __restrict__ row_partial) {
    __shared__ float s1[NWAVES], s2[NWAVES];
    const int wave = threadIdx.x >> 6;
    const int lane = threadIdx.x & 63;
    const int row0 = blockIdx.x * ROWS_PER_BLOCK;

    for (int r = 0; r < ROWS_PER_BLOCK; ++r) {
        const int row = row0 + r;
        const float4* rp = reinterpret_cast<const float4*>(logits + (size_t)row * VOCAB);

        // Issue the target gather early (thread 0); latency hides under the stream.
        float tv = 0.0f;
        if (threadIdx.x == 0) {
            const int t = target[row];
            tv = logits[(size_t)row * VOCAB + (size_t)t];
        }

        // 8000 float4 per row / 1024 threads: 7-8 iterations per thread.
        float m1 = -INFINITY, m2 = -INFINITY;
        for (int i = threadIdx.x; i < VOCAB / 4; i += TPB) {
            float4 v = rp[i];
            m2 = fmaxf(m2, fminf(m1, v.x)); m1 = fmaxf(m1, v.x);
            m2 = fmaxf(m2, fminf(m1, v.y)); m1 = fmaxf(m1, v.y);
            m2 = fmaxf(m2, fminf(m1, v.z)); m1 = fmaxf(m1, v.z);
            m2 = fmaxf(m2, fminf(m1, v.w)); m1 = fmaxf(m1, v.w);
        }

        // 64-lane butterfly reduction of the (m1, m2) pair
        #pragma unroll
        for (int off = 32; off > 0; off >>= 1) {
            float o1 = __shfl_xor(m1, off, 64);
            float o2 = __shfl_xor(m2, off, 64);
            float nm1 = fmaxf(m1, o1);
            float nm2 = fmaxf(fminf(m1, o1), fmaxf(m2, o2));
            m1 = nm1; m2 = nm2;
        }

        if (lane == 0) { s1[wave] = m1; s2[wave] = m2; }
        __syncthreads();

        if (threadIdx.x == 0) {
            m1 = s1[0]; m2 = s2[0];
            #pragma unroll
            for (int w = 1; w < NWAVES; ++w) {
                float o1 = s1[w], o2 = s2[w];
                float nm1 = fmaxf(m1, o1);
                float nm2 = fmaxf(fminf(m1, o1), fmaxf(m2, o2));
                m1 = nm1; m2 = nm2;
            }
            row_partial[row] = m1 + m2 - 2.0f * tv;
        }
        __syncthreads();   // s1/s2 reused next row
    }
}

__global__ __launch_bounds__(256) void cce_reduce_kernel(const float* __restrict__ row_partial,
                                                         float* __restrict__ out) {
    float s = 0.0f;
    for (int i = threadIdx.x; i < NROWS; i += 256) s += row_partial[i];
    #pragma unroll
    for (int off = 32; off > 0; off >>= 1) s += __shfl_xor(s, off, 64);

    __shared__ float ws[4];
    const int wave = threadIdx.x >> 6;
    const int lane = threadIdx.x & 63;
    if (lane == 0) ws[wave] = s;
    __syncthreads();
    if (threadIdx.x == 0) out[0] = ws[0] + ws[1] + ws[2] + ws[3];
}

extern "C" void kernel_launch(void* const* d_in, const int* in_sizes, int n_in,
                              void* d_out, int out_size, void* d_ws, size_t ws_size,
                              hipStream_t stream) {
    const float* logits = (const float*)d_in[0];
    const int* target = (const int*)d_in[1];
    float* out = (float*)d_out;
    float* row_partial = (float*)d_ws;  // NROWS floats = 32 KiB

    cce_row_kernel<<<NBLOCKS, TPB, 0, stream>>>(logits, target, row_partial);
    cce_reduce_kernel<<<1, 256, 0, stream>>>(row_partial, out);
}